// Round 3
// baseline (445.762 us; speedup 1.0000x reference)
//
#include <hip/hip_runtime.h>

// Shapes (fixed per setup_inputs): n=1, C=256, t=8, h=64, w=64, heads=8, S=134
#define SS   134
#define HWP  4096     // h*w
#define THW  32768    // t*h*w

typedef float f32x4 __attribute__((ext_vector_type(4)));
typedef short bf16x8 __attribute__((ext_vector_type(8)));
typedef short bf16x4 __attribute__((ext_vector_type(4)));

__device__ __forceinline__ float vget(const float4& v, int j) {
  return j == 0 ? v.x : j == 1 ? v.y : j == 2 ? v.z : v.w;
}

__device__ __forceinline__ unsigned short f2bf(float f) {
  unsigned int u = __float_as_uint(f);
  u += 0x7fff + ((u >> 16) & 1);  // RNE (inputs are finite normals)
  return (unsigned short)(u >> 16);
}

// ---------------------------------------------------------------------------
// 1x1 conv as bf16-MFMA GEMM: PV[o][x] = sum_c W[o][c] * V[c][x] + bias[o]
// M=256 (o, full per block), N=32 (x per block), K=256 in chunks of 32.
// v2: no min-waves bound (let compiler pick VGPRs -- the (256,4) cap likely
// forced scratch spills), staging unroll reduced to 2 to cut live ranges.
// ---------------------------------------------------------------------------
__global__ __launch_bounds__(256) void conv1x1_v2(
    const float* __restrict__ V, const float* __restrict__ W,
    const float* __restrict__ bias, float* __restrict__ PV) {
  __shared__ unsigned short sW[256 * 40];  // [o][c-k0], bf16, row stride 40
  __shared__ unsigned short sV[32 * 40];   // [x][c-k0], bf16 (transposed)
  const int tid = threadIdx.x;
  const int x0 = blockIdx.x * 32;
  const int lane = tid & 63;
  const int wv = tid >> 6;   // wave 0..3
  const int m = lane & 15;   // MFMA free-dim index
  const int q = lane >> 4;   // MFMA quad 0..3

  f32x4 acc[4][2];
#pragma unroll
  for (int i = 0; i < 4; ++i)
#pragma unroll
    for (int j = 0; j < 2; ++j)
      acc[i][j] = (f32x4){0.f, 0.f, 0.f, 0.f};

  for (int k0 = 0; k0 < 256; k0 += 32) {
    // stage W chunk: 256 o x 32 c fp32 -> bf16 LDS [o][c]
#pragma unroll 2
    for (int r = 0; r < 8; ++r) {
      const int f = r * 256 + tid;
      const int o = f >> 3;
      const int c4 = (f & 7) * 4;
      const float4 w4 = *(const float4*)&W[o * 256 + k0 + c4];
      bf16x4 b;
      b.x = (short)f2bf(w4.x);
      b.y = (short)f2bf(w4.y);
      b.z = (short)f2bf(w4.z);
      b.w = (short)f2bf(w4.w);
      *(bf16x4*)&sW[o * 40 + c4] = b;
    }
    // stage V chunk: 32 c x 32 x fp32 -> transposed bf16 LDS [x][c]
    {
      const int c = tid >> 3;          // 0..31
      const int x4 = (tid & 7) * 4;    // 0..28
      const float4 v4 = *(const float4*)&V[(size_t)(k0 + c) * THW + x0 + x4];
      sV[(x4 + 0) * 40 + c] = f2bf(v4.x);
      sV[(x4 + 1) * 40 + c] = f2bf(v4.y);
      sV[(x4 + 2) * 40 + c] = f2bf(v4.z);
      sV[(x4 + 3) * 40 + c] = f2bf(v4.w);
    }
    __syncthreads();
    bf16x8 fa[4], fb[2];
#pragma unroll
    for (int i = 0; i < 4; ++i)
      fa[i] = *(const bf16x8*)&sW[(wv * 64 + i * 16 + m) * 40 + q * 8];
#pragma unroll
    for (int j = 0; j < 2; ++j)
      fb[j] = *(const bf16x8*)&sV[(j * 16 + m) * 40 + q * 8];
#pragma unroll
    for (int i = 0; i < 4; ++i)
#pragma unroll
      for (int j = 0; j < 2; ++j)
        acc[i][j] = __builtin_amdgcn_mfma_f32_16x16x32_bf16(fa[i], fb[j], acc[i][j], 0, 0, 0);
    __syncthreads();
  }

  // epilogue: D[row=q*4+r][col=m]; add bias, store fp32
#pragma unroll
  for (int i = 0; i < 4; ++i) {
#pragma unroll
    for (int r = 0; r < 4; ++r) {
      const int o = wv * 64 + i * 16 + q * 4 + r;
      const float b = bias[o];
#pragma unroll
      for (int j = 0; j < 2; ++j)
        PV[(size_t)o * THW + x0 + j * 16 + m] = acc[i][j][r] + b;
    }
  }
}

// ---------------------------------------------------------------------------
// Criss-cross attention v2: latency-optimized scalar kernel.
// 512 threads: c = tid>>4 (one channel each, 0..31), wq4 = (tid&15)*4.
// Block = (hd, tq, hq-pair); acc[2 hq][4 wq] = 8 VGPRs.
// h-axis: segment-split at the two diagonal rows -> uniform rolling pointers,
// manual unroll-4 with batched loads (12 float4 in flight).
// w-axis: LDS-staged w-slab + rolling source pair, A prefetched 4 rows deep.
// Swizzle blk = hqp*64 + hd*8 + tq: 32 hq-siblings of (hd,tq) share an XCD.
// ---------------------------------------------------------------------------
__global__ __launch_bounds__(512, 4) void grid_attn_v2(
    const float* __restrict__ A, const float* __restrict__ PV,
    float* __restrict__ O) {
  const int blk = blockIdx.x;      // hqp*64 + hd*8 + tq, grid 2048
  const int tq = blk & 7;
  const int hd = (blk >> 3) & 7;
  const int hq0 = (blk >> 6) * 2;  // even, 0..62
  const int tid = threadIdx.x;
  const int wq4 = (tid & 15) * 4;
  const int c = tid >> 4;  // 0..31

  const float* __restrict__ Ab = A + (size_t)hd * SS * THW + (size_t)tq * HWP;
  const float* __restrict__ PVc = PV + (size_t)(hd * 32 + c) * THW;

  __shared__ float sPVw[32 * 2 * 68];  // [c][q][p], row stride 68

  // stage w-slices: pv[c, tq, hq0+q, p] for c=0..31, q=0..1, p=0..63
#pragma unroll
  for (int i = 0; i < 2; ++i) {
    const int fid = tid + i * 512;   // 0..1023 float4 id
    const int cq = fid >> 4;         // 0..63 (c*2+q)
    const int p4 = (fid & 15) * 4;   // 0..60
    const float* src = &PV[(size_t)(hd * 32 + (cq >> 1)) * THW + (size_t)tq * HWP +
                           (hq0 + (cq & 1)) * 64 + p4];
    *(float4*)&sPVw[cq * 68 + p4] = *(const float4*)src;
  }
  __syncthreads();

  float acc[2][4] = {};

  // ---- t axis ----
#pragma unroll
  for (int s = 0; s < 8; ++s) {
#pragma unroll
    for (int q = 0; q < 2; ++q) {
      const float4 a = *(const float4*)&Ab[(size_t)s * THW + (hq0 + q) * 64 + wq4];
      const float4 v = *(const float4*)&PVc[(size_t)s * HWP + (hq0 + q) * 64 + wq4];
#pragma unroll
      for (int j = 0; j < 4; ++j) acc[q][j] += vget(a, j) * vget(v, j);
    }
  }

  // ---- h axis (segmented, rolling pointers, unroll-4 batched loads) ----
  {
    const float* pA0 = Ab + (size_t)8 * THW + hq0 * 64 + wq4;  // q0 weight row
    const float* pA1 = pA0 + 64;                               // q1 weight row
    const float* pV = PVc + (size_t)tq * HWP + wq4;            // + p*64

    int p = 0;
    // segment 1: p in [0, hq0), idx = p for both q
    for (; p + 4 <= hq0; p += 4) {
      float4 a0[4], a1[4], vv[4];
#pragma unroll
      for (int u = 0; u < 4; ++u) {
        a0[u] = *(const float4*)(pA0 + (size_t)u * THW);
        a1[u] = *(const float4*)(pA1 + (size_t)u * THW);
        vv[u] = *(const float4*)(pV + (size_t)(p + u) * 64);
      }
#pragma unroll
      for (int u = 0; u < 4; ++u)
#pragma unroll
        for (int j = 0; j < 4; ++j) {
          acc[0][j] += vget(a0[u], j) * vget(vv[u], j);
          acc[1][j] += vget(a1[u], j) * vget(vv[u], j);
        }
      pA0 += 4 * (size_t)THW;
      pA1 += 4 * (size_t)THW;
    }
    for (; p < hq0; ++p) {
      const float4 a0 = *(const float4*)pA0;
      const float4 a1 = *(const float4*)pA1;
      const float4 vv = *(const float4*)(pV + (size_t)p * 64);
#pragma unroll
      for (int j = 0; j < 4; ++j) {
        acc[0][j] += vget(a0, j) * vget(vv, j);
        acc[1][j] += vget(a1, j) * vget(vv, j);
      }
      pA0 += THW;
      pA1 += THW;
    }
    // p == hq0: q0 is diagonal (skip), q1 uses idx = hq0
    {
      const float4 a1 = *(const float4*)pA1;
      const float4 vv = *(const float4*)(pV + (size_t)hq0 * 64);
#pragma unroll
      for (int j = 0; j < 4; ++j) acc[1][j] += vget(a1, j) * vget(vv, j);
      pA1 += THW;
    }
    // p == hq0+1: q1 is diagonal (skip), q0 uses idx = hq0
    {
      const float4 a0 = *(const float4*)pA0;
      const float4 vv = *(const float4*)(pV + (size_t)(hq0 + 1) * 64);
#pragma unroll
      for (int j = 0; j < 4; ++j) acc[0][j] += vget(a0, j) * vget(vv, j);
      pA0 += THW;
    }
    // segment 3: p in [hq0+2, 64), idx = p-1 for both q
    p = hq0 + 2;
    for (; p + 4 <= 64; p += 4) {
      float4 a0[4], a1[4], vv[4];
#pragma unroll
      for (int u = 0; u < 4; ++u) {
        a0[u] = *(const float4*)(pA0 + (size_t)u * THW);
        a1[u] = *(const float4*)(pA1 + (size_t)u * THW);
        vv[u] = *(const float4*)(pV + (size_t)(p + u) * 64);
      }
#pragma unroll
      for (int u = 0; u < 4; ++u)
#pragma unroll
        for (int j = 0; j < 4; ++j) {
          acc[0][j] += vget(a0[u], j) * vget(vv[u], j);
          acc[1][j] += vget(a1[u], j) * vget(vv[u], j);
        }
      pA0 += 4 * (size_t)THW;
      pA1 += 4 * (size_t)THW;
    }
    for (; p < 64; ++p) {
      const float4 a0 = *(const float4*)pA0;
      const float4 a1 = *(const float4*)pA1;
      const float4 vv = *(const float4*)(pV + (size_t)p * 64);
#pragma unroll
      for (int j = 0; j < 4; ++j) {
        acc[0][j] += vget(a0, j) * vget(vv, j);
        acc[1][j] += vget(a1, j) * vget(vv, j);
      }
      pA0 += THW;
      pA1 += THW;
    }
  }

  // ---- w axis (weight rows r, rolling source pair, A prefetch x4) ----
  {
    const int base0 = (c * 2 + 0) * 68;
    const int base1 = (c * 2 + 1) * 68;
    float cur0 = sPVw[base0];
    float cur1 = sPVw[base1];
    const float* pAw = Ab + (size_t)71 * THW + hq0 * 64 + wq4;
    int r = 0;
    for (; r + 4 <= 63; r += 4) {
      float4 a0[4], a1[4];
#pragma unroll
      for (int u = 0; u < 4; ++u) {
        a0[u] = *(const float4*)(pAw + (size_t)u * THW);
        a1[u] = *(const float4*)(pAw + (size_t)u * THW + 64);
      }
#pragma unroll
      for (int u = 0; u < 4; ++u) {
        const int rr = r + u;
        const float nxt0 = sPVw[base0 + rr + 1];
        const float nxt1 = sPVw[base1 + rr + 1];
#pragma unroll
        for (int j = 0; j < 4; ++j) {
          const bool lt = (rr < wq4 + j);  // source p = lt ? rr : rr+1
          acc[0][j] += vget(a0[u], j) * (lt ? cur0 : nxt0);
          acc[1][j] += vget(a1[u], j) * (lt ? cur1 : nxt1);
        }
        cur0 = nxt0;
        cur1 = nxt1;
      }
      pAw += 4 * (size_t)THW;
    }
    for (; r < 63; ++r) {
      const float4 a0 = *(const float4*)pAw;
      const float4 a1 = *(const float4*)(pAw + 64);
      const float nxt0 = sPVw[base0 + r + 1];
      const float nxt1 = sPVw[base1 + r + 1];
#pragma unroll
      for (int j = 0; j < 4; ++j) {
        const bool lt = (r < wq4 + j);
        acc[0][j] += vget(a0, j) * (lt ? cur0 : nxt0);
        acc[1][j] += vget(a1, j) * (lt ? cur1 : nxt1);
      }
      cur0 = nxt0;
      cur1 = nxt1;
      pAw += THW;
    }
  }

  // ---- store ----
#pragma unroll
  for (int q = 0; q < 2; ++q) {
    float4 r;
    r.x = acc[q][0];
    r.y = acc[q][1];
    r.z = acc[q][2];
    r.w = acc[q][3];
    *(float4*)&O[(size_t)(hd * 32 + c) * THW + (size_t)tq * HWP + (hq0 + q) * 64 + wq4] = r;
  }
}

extern "C" void kernel_launch(void* const* d_in, const int* in_sizes, int n_in,
                              void* d_out, int out_size, void* d_ws, size_t ws_size,
                              hipStream_t stream) {
  const float* A = (const float*)d_in[0];     // [8*134][8][64][64]
  const float* V = (const float*)d_in[1];     // [256][8][64][64]
  const float* W = (const float*)d_in[2];     // [256][256] (o, c)
  const float* bias = (const float*)d_in[3];  // [256]
  float* out = (float*)d_out;                 // [256][8][64][64]
  float* pv = (float*)d_ws;                   // 32 MB scratch: pv[o][t][h][w]

  conv1x1_v2<<<dim3(1024), 256, 0, stream>>>(V, W, bias, pv);
  grid_attn_v2<<<dim3(2048), 512, 0, stream>>>(A, pv, out);
}

// Round 4
// 380.056 us; speedup vs baseline: 1.1729x; 1.1729x over previous
//
#include <hip/hip_runtime.h>

// Shapes (fixed per setup_inputs): n=1, C=256, t=8, h=64, w=64, heads=8, S=134
#define SS   134
#define HWP  4096     // h*w
#define THW  32768    // t*h*w

typedef float f32x4 __attribute__((ext_vector_type(4)));
typedef short bf16x8 __attribute__((ext_vector_type(8)));
typedef short bf16x4 __attribute__((ext_vector_type(4)));

__device__ __forceinline__ unsigned short f2bf(float f) {
  unsigned int u = __float_as_uint(f);
  u += 0x7fff + ((u >> 16) & 1);  // RNE (inputs are finite normals)
  return (unsigned short)(u >> 16);
}

// ---------------------------------------------------------------------------
// 1x1 conv as bf16-MFMA GEMM: PV[o][x] = sum_c W[o][c] * V[c][x] + bias[o]
// (unchanged from R3)
// ---------------------------------------------------------------------------
__global__ __launch_bounds__(256) void conv1x1_v2(
    const float* __restrict__ V, const float* __restrict__ W,
    const float* __restrict__ bias, float* __restrict__ PV) {
  __shared__ unsigned short sW[256 * 40];  // [o][c-k0], bf16, row stride 40
  __shared__ unsigned short sV[32 * 40];   // [x][c-k0], bf16 (transposed)
  const int tid = threadIdx.x;
  const int x0 = blockIdx.x * 32;
  const int lane = tid & 63;
  const int wv = tid >> 6;   // wave 0..3
  const int m = lane & 15;   // MFMA free-dim index
  const int q = lane >> 4;   // MFMA quad 0..3

  f32x4 acc[4][2];
#pragma unroll
  for (int i = 0; i < 4; ++i)
#pragma unroll
    for (int j = 0; j < 2; ++j)
      acc[i][j] = (f32x4){0.f, 0.f, 0.f, 0.f};

  for (int k0 = 0; k0 < 256; k0 += 32) {
#pragma unroll 2
    for (int r = 0; r < 8; ++r) {
      const int f = r * 256 + tid;
      const int o = f >> 3;
      const int c4 = (f & 7) * 4;
      const float4 w4 = *(const float4*)&W[o * 256 + k0 + c4];
      bf16x4 b;
      b.x = (short)f2bf(w4.x);
      b.y = (short)f2bf(w4.y);
      b.z = (short)f2bf(w4.z);
      b.w = (short)f2bf(w4.w);
      *(bf16x4*)&sW[o * 40 + c4] = b;
    }
    {
      const int c = tid >> 3;          // 0..31
      const int x4 = (tid & 7) * 4;    // 0..28
      const float4 v4 = *(const float4*)&V[(size_t)(k0 + c) * THW + x0 + x4];
      sV[(x4 + 0) * 40 + c] = f2bf(v4.x);
      sV[(x4 + 1) * 40 + c] = f2bf(v4.y);
      sV[(x4 + 2) * 40 + c] = f2bf(v4.z);
      sV[(x4 + 3) * 40 + c] = f2bf(v4.w);
    }
    __syncthreads();
    bf16x8 fa[4], fb[2];
#pragma unroll
    for (int i = 0; i < 4; ++i)
      fa[i] = *(const bf16x8*)&sW[(wv * 64 + i * 16 + m) * 40 + q * 8];
#pragma unroll
    for (int j = 0; j < 2; ++j)
      fb[j] = *(const bf16x8*)&sV[(j * 16 + m) * 40 + q * 8];
#pragma unroll
    for (int i = 0; i < 4; ++i)
#pragma unroll
      for (int j = 0; j < 2; ++j)
        acc[i][j] = __builtin_amdgcn_mfma_f32_16x16x32_bf16(fa[i], fb[j], acc[i][j], 0, 0, 0);
    __syncthreads();
  }

#pragma unroll
  for (int i = 0; i < 4; ++i) {
#pragma unroll
    for (int r = 0; r < 4; ++r) {
      const int o = wv * 64 + i * 16 + q * 4 + r;
      const float b = bias[o];
#pragma unroll
      for (int j = 0; j < 2; ++j)
        PV[(size_t)o * THW + x0 + j * 16 + m] = acc[i][j][r] + b;
    }
  }
}

// ---------------------------------------------------------------------------
// t + h axes. Block = (hd, tq, w-strip of 8). 256 thr:
//   w4 = (tid&1)*4 (2 w-quads), q16 = (tid>>1)&15, cg = tid>>5 (channels
//   cg + 8*ci, ci=0..3). acc[4 qq][4 ci] f32x4 over w.
// pv h-slab [32c][64p][8w] fp32 in LDS (64 KB): h-source reads are pure
// LDS broadcasts. A h-row select per (p,qq): row = 8 + p - (q<p), a=0 if q==p.
// ---------------------------------------------------------------------------
__global__ __launch_bounds__(256) void attn_th(
    const float* __restrict__ A, const float* __restrict__ PV,
    float* __restrict__ O) {
  const int b = blockIdx.x;  // wb + 8*tq + 64*hd, grid 512
  const int wb = b & 7;
  const int tq = (b >> 3) & 7;
  const int hd = b >> 6;
  const int tid = threadIdx.x;
  const int w4 = (tid & 1) * 4;
  const int q16 = (tid >> 1) & 15;
  const int cg = tid >> 5;  // 0..7

  __shared__ float slab[32 * 64 * 8];  // [c][p][w8]

  const float* __restrict__ Ab = A + (size_t)hd * SS * THW + (size_t)tq * HWP;
  const size_t pvh = (size_t)hd * 32 * THW;

  // stage pv h-slab: pv[hd*32+c][tq][p][wb*8 + w]
#pragma unroll 4
  for (int i = 0; i < 16; ++i) {
    const int fid = tid + i * 256;  // 0..4095
    const int ws = (fid & 1) * 4;
    const int p = (fid >> 1) & 63;
    const int c = fid >> 7;  // 0..31
    *(f32x4*)&slab[(c * 64 + p) * 8 + ws] =
        *(const f32x4*)&PV[pvh + (size_t)c * THW + (size_t)tq * HWP + p * 64 + wb * 8 + ws];
  }
  __syncthreads();

  f32x4 acc[4][4];  // [qq][ci]
#pragma unroll
  for (int i = 0; i < 4; ++i)
#pragma unroll
    for (int j = 0; j < 4; ++j)
      acc[i][j] = (f32x4){0.f, 0.f, 0.f, 0.f};

  // ---- t axis (pv from global, L2-warm) ----
  for (int s = 0; s < 8; ++s) {
#pragma unroll
    for (int qq = 0; qq < 4; ++qq) {
      const int q = qq * 16 + q16;
      const f32x4 a = *(const f32x4*)&Ab[(size_t)s * THW + q * 64 + wb * 8 + w4];
#pragma unroll
      for (int ci = 0; ci < 4; ++ci) {
        const int c = cg + ci * 8;
        const f32x4 v =
            *(const f32x4*)&PV[pvh + (size_t)c * THW + (size_t)s * HWP + q * 64 + wb * 8 + w4];
        acc[qq][ci] += a * v;
      }
    }
  }

  // ---- h axis ----
  const float* __restrict__ Ah = Ab + (size_t)8 * THW + wb * 8 + w4;
#pragma unroll 2
  for (int p = 0; p < 64; ++p) {
    f32x4 av[4];
#pragma unroll
    for (int qq = 0; qq < 4; ++qq) {
      const int q = qq * 16 + q16;
      const int row = p - (q < p ? 1 : 0);  // 0..62 (p==q garbage, masked)
      f32x4 a = *(const f32x4*)&Ah[(size_t)row * THW + q * 64];
      if (q == p) a = (f32x4){0.f, 0.f, 0.f, 0.f};
      av[qq] = a;
    }
    f32x4 vv[4];
#pragma unroll
    for (int ci = 0; ci < 4; ++ci)
      vv[ci] = *(const f32x4*)&slab[((cg + ci * 8) * 64 + p) * 8 + w4];
#pragma unroll
    for (int qq = 0; qq < 4; ++qq)
#pragma unroll
      for (int ci = 0; ci < 4; ++ci)
        acc[qq][ci] += av[qq] * vv[ci];
  }

  // ---- store ----
#pragma unroll
  for (int qq = 0; qq < 4; ++qq) {
    const int q = qq * 16 + q16;
#pragma unroll
    for (int ci = 0; ci < 4; ++ci) {
      const int c = cg + ci * 8;
      *(f32x4*)&O[pvh + (size_t)c * THW + (size_t)tq * HWP + q * 64 + wb * 8 + w4] =
          acc[qq][ci];
    }
  }
}

// ---------------------------------------------------------------------------
// w axis, read-modify-write on O. Block = (hd, tq, h-strip of 4). 256 thr:
//   wq = tid&63 (lane = output w), cg = tid>>6 (channels cg + 4*ci, ci=0..7).
// pv w-slab [32c][64pw][4h] fp32 in LDS (32 KB): source reads are uniform
// f32x4 broadcasts. Weight row per (p, lane): r = 71 + p - (wq<=p), a=0 if
// p==wq (wq<=p avoids OOB row 134 at p==wq==63).
// acc[8 ci] f32x4 over h.
// ---------------------------------------------------------------------------
__global__ __launch_bounds__(256) void attn_w(
    const float* __restrict__ A, const float* __restrict__ PV,
    float* __restrict__ O) {
  const int b = blockIdx.x;  // hb + 16*tq + 128*hd, grid 1024
  const int hb = b & 15;
  const int tq = (b >> 4) & 7;
  const int hd = b >> 7;
  const int tid = threadIdx.x;
  const int wq = tid & 63;
  const int cg = tid >> 6;  // 0..3
  const int h0 = hb * 4;

  __shared__ float slab[32 * 64 * 4];  // [c][pw][h4]

  const float* __restrict__ Ab = A + (size_t)hd * SS * THW + (size_t)tq * HWP;
  const size_t pvh = (size_t)hd * 32 * THW;

  // stage pv w-slab (transpose w<->h minor dims)
#pragma unroll 4
  for (int i = 0; i < 8; ++i) {
    const int fid = tid + i * 256;     // 0..2047
    const int w4s = (fid & 15) * 4;    // 0..60
    const int h = (fid >> 4) & 3;      // 0..3
    const int c = fid >> 6;            // 0..31
    const f32x4 v =
        *(const f32x4*)&PV[pvh + (size_t)c * THW + (size_t)tq * HWP + (h0 + h) * 64 + w4s];
    slab[(c * 64 + w4s + 0) * 4 + h] = v.x;
    slab[(c * 64 + w4s + 1) * 4 + h] = v.y;
    slab[(c * 64 + w4s + 2) * 4 + h] = v.z;
    slab[(c * 64 + w4s + 3) * 4 + h] = v.w;
  }

  // prefetch current O tile (RMW) while staging completes
  f32x4 racc[8];
#pragma unroll
  for (int ci = 0; ci < 8; ++ci) {
    const int c = cg + ci * 4;
    f32x4 r;
#pragma unroll
    for (int hh = 0; hh < 4; ++hh)
      r[hh] = O[pvh + (size_t)c * THW + (size_t)tq * HWP + (h0 + hh) * 64 + wq];
    racc[ci] = r;
  }
  __syncthreads();

#pragma unroll 2
  for (int p = 0; p < 64; ++p) {
    const int row = 71 + p - (wq <= p ? 1 : 0);  // 70..133, in-bounds always
    const float* pa = Ab + (size_t)row * THW + h0 * 64 + wq;
    f32x4 a;
    a.x = pa[0];
    a.y = pa[64];
    a.z = pa[128];
    a.w = pa[192];
    if (p == wq) a = (f32x4){0.f, 0.f, 0.f, 0.f};
#pragma unroll
    for (int ci = 0; ci < 8; ++ci) {
      const f32x4 v = *(const f32x4*)&slab[(cg + ci * 4) * 256 + p * 4];
      racc[ci] += a * v;
    }
  }

  // ---- store (RMW result) ----
#pragma unroll
  for (int ci = 0; ci < 8; ++ci) {
    const int c = cg + ci * 4;
#pragma unroll
    for (int hh = 0; hh < 4; ++hh)
      O[pvh + (size_t)c * THW + (size_t)tq * HWP + (h0 + hh) * 64 + wq] = racc[ci][hh];
  }
}

extern "C" void kernel_launch(void* const* d_in, const int* in_sizes, int n_in,
                              void* d_out, int out_size, void* d_ws, size_t ws_size,
                              hipStream_t stream) {
  const float* A = (const float*)d_in[0];     // [8*134][8][64][64]
  const float* V = (const float*)d_in[1];     // [256][8][64][64]
  const float* W = (const float*)d_in[2];     // [256][256] (o, c)
  const float* bias = (const float*)d_in[3];  // [256]
  float* out = (float*)d_out;                 // [256][8][64][64]
  float* pv = (float*)d_ws;                   // 32 MB scratch: pv[o][t][h][w]

  conv1x1_v2<<<dim3(1024), 256, 0, stream>>>(V, W, bias, pv);
  attn_th<<<dim3(512), 256, 0, stream>>>(A, pv, out);
  attn_w<<<dim3(1024), 256, 0, stream>>>(A, pv, out);
}